// Round 14
// baseline (119.546 us; speedup 1.0000x reference)
//
#include <hip/hip_runtime.h>
#include <math.h>

#define M_DIM 8192
#define K_DIM 2048
#define N_DIM 4096
#define TOPK  82

typedef short short8 __attribute__((ext_vector_type(8)));
typedef float f32x4 __attribute__((ext_vector_type(4)));
typedef float f32x16 __attribute__((ext_vector_type(16)));
typedef int   i32x4 __attribute__((ext_vector_type(4)));
typedef int   i32x8 __attribute__((ext_vector_type(8)));
typedef unsigned short ushort_t;
typedef unsigned long long u64;

__device__ __forceinline__ unsigned short f2bf(float f){
  unsigned u = __float_as_uint(f);
  unsigned r = (u + 0x7FFFu + ((u >> 16) & 1u)) >> 16;  // RNE; exact for 0.0/1.0
  return (unsigned short)r;
}

// async global->LDS, 16B per lane. LDS dest = wave-uniform base + lane*16.
__device__ __forceinline__ void gload16(const void* g, void* l){
  __builtin_amdgcn_global_load_lds(
      (const __attribute__((address_space(1))) unsigned int*)g,
      (__attribute__((address_space(3))) unsigned int*)l,
      16, 0, 0);
}

// MX-fp4 MFMA 32x32x64, scale = 1.0 (E8M0 = 127). Verified round 13.
__device__ __forceinline__ f32x16 mfma32_fp4(i32x4 a, i32x4 b, f32x16 c){
  i32x8 A; A[0]=a[0]; A[1]=a[1]; A[2]=a[2]; A[3]=a[3]; A[4]=0; A[5]=0; A[6]=0; A[7]=0;
  i32x8 B; B[0]=b[0]; B[1]=b[1]; B[2]=b[2]; B[3]=b[3]; B[4]=0; B[5]=0; B[6]=0; B[7]=0;
  return __builtin_amdgcn_mfma_scale_f32_32x32x64_f8f6f4(
      A, B, c, 4, 4, 0, 0x7F7F7F7F, 0, 0x7F7F7F7F);
}

// ---- fused prep: A-pack (0..8191) | B-pack (8192..8703) | boost (8704) ----
// fp4 nibble: 1.0 -> 0x2, 0.0 -> 0x0 (e2m1).
// B4W layout (wave-read order): for 32-col group g = global_col/32, K-tile kt,
// 16-B chunk c (k elems [c*32, c*32+32)), col-in-group:
//   byte = ((g*16 + kt)*4 + c)*512 + (col&31)*16
// A wave's b-fragment {chunks c,c+1} x 32 cols is then 1 KB contiguous and the
// per-lane bytes (lane -> col lane&31, chunk c+(lane>>5)) match the verified
// round-13 LDS fragment exactly.
__global__ __launch_bounds__(256) void prep_kernel(const float* __restrict__ X,
                                                   const float* __restrict__ Cn,
                                                   const float* __restrict__ avg,
                                                   unsigned* __restrict__ A4,
                                                   unsigned char* __restrict__ B4,
                                                   double* __restrict__ boost){
  int bid = blockIdx.x;
  int tid = threadIdx.x;
  if (bid < 8192){
    size_t e0 = ((size_t)bid*256 + tid)*8;
    float4 f0 = *(const float4*)&X[e0];
    float4 f1 = *(const float4*)&X[e0 + 4];
    unsigned dw = (f0.x!=0.f?2u:0u)        | ((f0.y!=0.f?2u:0u)<<4)
                | ((f0.z!=0.f?2u:0u)<<8)   | ((f0.w!=0.f?2u:0u)<<12)
                | ((f1.x!=0.f?2u:0u)<<16)  | ((f1.y!=0.f?2u:0u)<<20)
                | ((f1.z!=0.f?2u:0u)<<24)  | ((f1.w!=0.f?2u:0u)<<28);
    A4[(size_t)bid*256 + tid] = dw;
  } else if (bid < 8704){
    __shared__ float s[128*132];
    int b = bid - 8192;
    int bk = b & 15, bn = b >> 4;          // bk = K-tile (128 elems), bn = 128-col tile
    int rr = tid >> 5, cc = (tid & 31)*4;
    #pragma unroll
    for (int p = 0; p < 16; ++p){
      int r = p*8 + rr;
      float4 f = *(const float4*)&Cn[((size_t)(bk*128 + r))*N_DIM + bn*128 + cc];
      *(float4*)&s[r*132 + cc] = f;
    }
    __syncthreads();
    int nn = tid >> 1, kh = tid & 1;       // col in tile (0..127), k-half 0/1
    unsigned dws[8];
    #pragma unroll
    for (int d = 0; d < 8; ++d){
      unsigned v = 0;
      #pragma unroll
      for (int i = 0; i < 8; ++i){
        int k = kh*64 + d*8 + i;
        v |= (s[k*132 + nn] != 0.f ? 2u : 0u) << (4*i);
      }
      dws[d] = v;
    }
    uint4 o0; o0.x=dws[0]; o0.y=dws[1]; o0.z=dws[2]; o0.w=dws[3];   // chunk 2*kh
    uint4 o1; o1.x=dws[4]; o1.y=dws[5]; o1.z=dws[6]; o1.w=dws[7];   // chunk 2*kh+1
    int g = bn*4 + (nn >> 5);              // global_col / 32
    size_t base = (((size_t)g*16 + bk)*4 + 2*kh)*512 + (size_t)(nn & 31)*16;
    *(uint4*)&B4[base]       = o0;
    *(uint4*)&B4[base + 512] = o1;
  } else {
    __shared__ double sp[4];
    __shared__ double stot;
    int lane = tid & 63, w = tid >> 6;
    double s = 0.0;
    for (int i = 0; i < 16; ++i) s += (double)avg[tid + 256*i];
    for (int off = 32; off > 0; off >>= 1) s += __shfl_down(s, off, 64);
    if (lane == 0) sp[w] = s;
    __syncthreads();
    if (tid == 0) stot = sp[0] + sp[1] + sp[2] + sp[3];
    __syncthreads();
    double tot = stot;
    for (int i = 0; i < 16; ++i){
      int j = tid + 256*i;
      double a = (double)avg[j];
      double nb = (tot - a) / 4095.0;
      boost[j] = exp(-100.0 * (a - nb));
    }
  }
}

// ---- fp4 GEMM, 256x256, 32x32x64, B direct from L2 (no B-LDS) --------------
// A: LDS dbuf 2x16 KB, paired-row swizzle + gload_lds (verified r12/r13).
// B: wave-order B4W layout -> each b-fragment is one coalesced 1 KB global
// load (lane*16 contiguous) from the L2-resident 4 MB array. Per-tile LDS
// reads drop 12 -> 8, staging loads halve.
template<typename OUT_T>
__global__ __launch_bounds__(512, 2) void gemm7_kernel(const unsigned char* __restrict__ A4,
                                                       const unsigned char* __restrict__ B4,
                                                       OUT_T* __restrict__ out){
  __shared__ unsigned char smem[65536];   // A dbuf: c*16384 (32 KB); epilogue reuses 64 KB
  int tid = threadIdx.x;
  int lane = tid & 63, w = tid >> 6;
  unsigned bid = blockIdx.x;
  unsigned sw = (bid & 7u)*64u + (bid >> 3);   // XCD swizzle, 512%8==0 bijective
  int bn = sw & 15, bm = sw >> 4;
  int brow = bm*256, bcol = bn*256;
  int wr = w >> 2, wc = w & 3;
  int fr = lane & 31, fq2 = lane >> 5;
  int pl = lane >> 3;                          // staging pair within 16-row group
  int sx = (lane & 7) ^ (pl & 7);
  int sp2 = sx >> 2;                           // source row parity
  int sc = sx & 3;                             // source chunk

  f32x16 acc[4][2];
  #pragma unroll
  for (int m = 0; m < 4; ++m)
    #pragma unroll
    for (int n = 0; n < 2; ++n)
      #pragma unroll
      for (int r = 0; r < 16; ++r) acc[m][n][r] = 0.f;

  auto stage = [&](int c, int kt){             // A only
    unsigned char* Ad = smem + c*16384;
    int kbase = kt*64;
    #pragma unroll
    for (int i = 0; i < 2; ++i){
      int R0 = w*32 + i*16;
      int r  = R0 + 2*pl + sp2;
      gload16(A4 + ((size_t)(brow + r))*1024 + kbase + sc*16, Ad + R0*64);
    }
  };

  auto lds_off = [&](int r, int c)->int{       // row r, 16-B chunk c (0..3)
    int pair = r >> 1;
    int s = (((r & 1) << 2) + c) ^ (pair & 7);
    return pair*128 + s*16;
  };

  // per-wave B fragment bases (g = global_col/32 = bn*8 + wc*2 + n)
  const unsigned char* bbase[2];
  #pragma unroll
  for (int n = 0; n < 2; ++n)
    bbase[n] = B4 + (((size_t)(bn*8 + wc*2 + n)*16)*4)*512 + (size_t)lane*16;

  stage(0, 0);
  __syncthreads();
  int cur = 0;
  for (int t = 0; t < 16; ++t){
    // B fragments for tile t: coalesced 1 KB loads from L2 (chunks {0,1}, {2,3})
    i32x4 b0[2], b1[2];
    #pragma unroll
    for (int n = 0; n < 2; ++n){
      const unsigned char* bq = bbase[n] + (size_t)t*2048;
      b0[n] = *(const i32x4*)(bq);
      b1[n] = *(const i32x4*)(bq + 1024);
    }
    if (t < 15) stage(cur ^ 1, t + 1);     // A prefetch flies under compute
    const unsigned char* Ah = smem + cur*16384;
    i32x4 a0[4], a1[4];
    #pragma unroll
    for (int m = 0; m < 4; ++m){
      int r = wr*128 + m*32 + fr;
      a0[m] = *(const i32x4*)&Ah[lds_off(r, fq2)];
      a1[m] = *(const i32x4*)&Ah[lds_off(r, 2 + fq2)];
    }
    #pragma unroll
    for (int m = 0; m < 4; ++m)
      #pragma unroll
      for (int n = 0; n < 2; ++n)
        acc[m][n] = mfma32_fp4(a0[m], b0[n], acc[m][n]);
    #pragma unroll
    for (int m = 0; m < 4; ++m)
      #pragma unroll
      for (int n = 0; n < 2; ++n)
        acc[m][n] = mfma32_fp4(a1[m], b1[n], acc[m][n]);
    __syncthreads();                       // drains A prefetch; protects buf reuse
    cur ^= 1;
  }

  if constexpr (sizeof(OUT_T) == 2){
    // u16 epilogue in two 64 KB passes (exact: counts are integers <= 2048)
    unsigned short* Ct = (unsigned short*)smem;
    #pragma unroll
    for (int p = 0; p < 2; ++p){
      if (wr == p){
        #pragma unroll
        for (int m = 0; m < 4; ++m)
          #pragma unroll
          for (int n = 0; n < 2; ++n)
            #pragma unroll
            for (int r = 0; r < 16; ++r){
              int lr = m*32 + (r & 3) + 8*(r >> 2) + 4*fq2;   // 0..127
              int lc = wc*64 + n*32 + fr;
              Ct[lr*256 + lc] = (unsigned short)(acc[m][n][r] + 0.5f);
            }
      }
      __syncthreads();
      #pragma unroll
      for (int q = 0; q < 8; ++q){
        int idx = q*8192 + tid*16;           // byte offset into 64 KB half
        int lr = idx >> 9;
        int lcb = idx & 511;
        char* gp = (char*)(out + ((size_t)(brow + p*128 + lr))*N_DIM + bcol) + lcb;
        *(uint4*)gp = *(const uint4*)&smem[idx];
      }
      __syncthreads();
    }
  } else {
    #pragma unroll
    for (int m = 0; m < 4; ++m)
      #pragma unroll
      for (int n = 0; n < 2; ++n)
        #pragma unroll
        for (int r = 0; r < 16; ++r){
          int row = brow + wr*128 + m*32 + (r & 3) + 8*(r >> 2) + 4*fq2;
          int col = bcol + wc*64 + n*32 + fr;
          out[((size_t)row)*N_DIM + col] = (OUT_T)acc[m][n][r];
        }
  }
}

// ---------------- fallback GEMM (tiny ws): bf16 reg-staged ------------------
__global__ __launch_bounds__(256) void gemm_fb_kernel(const float* __restrict__ X,
                                                      const float* __restrict__ Cn,
                                                      float* __restrict__ out){
  __shared__ ushort_t As[128*32];
  __shared__ ushort_t Bs[128*32];
  int tid = threadIdx.x;
  int bn = blockIdx.x & 31, bm = blockIdx.x >> 5;
  int brow = bm * 128, bcol = bn * 128;
  int lane = tid & 63, w = tid >> 6;
  int wr = w >> 1, wc = w & 1;
  int fr = lane & 15, fq = lane >> 4;
  f32x4 acc[4][4];
  for (int m = 0; m < 4; ++m)
    for (int n = 0; n < 4; ++n)
      acc[m][n] = (f32x4){0.f, 0.f, 0.f, 0.f};
  int r2 = tid >> 1, h = tid & 1;
  int kr = tid >> 3, seg = tid & 7;
  for (int kk = 0; kk < K_DIM; kk += 32){
    __syncthreads();
    const float* ga = X + ((size_t)(brow + r2))*K_DIM + kk + h*16;
    unsigned pk[8];
    for (int q = 0; q < 4; ++q){
      float4 f = *(const float4*)(ga + q*4);
      pk[q*2]   = (unsigned)f2bf(f.x) | ((unsigned)f2bf(f.y) << 16);
      pk[q*2+1] = (unsigned)f2bf(f.z) | ((unsigned)f2bf(f.w) << 16);
    }
    uint4 u0; u0.x = pk[0]; u0.y = pk[1]; u0.z = pk[2]; u0.w = pk[3];
    uint4 u1; u1.x = pk[4]; u1.y = pk[5]; u1.z = pk[6]; u1.w = pk[7];
    *(uint4*)&As[r2*32 + h*16]     = u0;
    *(uint4*)&As[r2*32 + h*16 + 8] = u1;
    const float* gb = Cn + ((size_t)(kk + kr))*N_DIM + bcol + seg*16;
    for (int q = 0; q < 4; ++q){
      float4 f = *(const float4*)(gb + q*4);
      Bs[(seg*16 + q*4 + 0)*32 + kr] = f2bf(f.x);
      Bs[(seg*16 + q*4 + 1)*32 + kr] = f2bf(f.y);
      Bs[(seg*16 + q*4 + 2)*32 + kr] = f2bf(f.z);
      Bs[(seg*16 + q*4 + 3)*32 + kr] = f2bf(f.w);
    }
    __syncthreads();
    short8 a[4], b[4];
    for (int m = 0; m < 4; ++m) a[m] = *(const short8*)&As[(wr*64 + m*16 + fr)*32 + fq*8];
    for (int n = 0; n < 4; ++n) b[n] = *(const short8*)&Bs[(wc*64 + n*16 + fr)*32 + fq*8];
    for (int m = 0; m < 4; ++m)
      for (int n = 0; n < 4; ++n)
        acc[m][n] = __builtin_amdgcn_mfma_f32_16x16x32_bf16(a[m], b[n], acc[m][n], 0, 0, 0);
  }
  for (int m = 0; m < 4; ++m)
    for (int n = 0; n < 4; ++n){
      int row = brow + wr*64 + m*16 + fq*4;
      int col = bcol + wc*64 + n*16 + fr;
      for (int j = 0; j < 4; ++j)
        out[((size_t)(row + j))*N_DIM + col] = acc[m][n][j];
    }
}

// ---------------- per-row exact top-82 -> one-hot (round-11, verified) ------
#define PIDX(x) ((x) + ((x) >> 5))
#define HSZ 4224

__device__ __forceinline__ void find_bin(const unsigned* hist, unsigned* wtot,
                                         int* pB, int* pK, int tid, int Kt){
  int lane = tid & 63, w = tid >> 6;
  unsigned s = 0;
  #pragma unroll
  for (int b = 0; b < 16; ++b) s += hist[PIDX(tid*16 + b)];
  unsigned S = s;
  #pragma unroll
  for (int off = 1; off < 64; off <<= 1){
    unsigned T = __shfl_down(S, off, 64);
    if (lane + off < 64) S += T;
  }
  if (lane == 0) wtot[w] = S;
  __syncthreads();
  unsigned above = 0;
  for (int w2 = w + 1; w2 < 4; ++w2) above += wtot[w2];
  unsigned St = S + above;
  unsigned Sn = St - s;
  if (St >= (unsigned)Kt && Sn < (unsigned)Kt){
    unsigned cum = Sn;
    for (int b = 15; b >= 0; --b){
      unsigned hb = hist[PIDX(tid*16 + b)];
      cum += hb;
      if (cum >= (unsigned)Kt){ *pB = tid*16 + b; *pK = Kt - (int)(cum - hb); break; }
    }
  }
  __syncthreads();
}

template<typename CT>
__global__ __launch_bounds__(256) void topk_kernel(const CT* __restrict__ cnt,
                                                   float* __restrict__ outp,
                                                   const double* __restrict__ boost){
  __shared__ unsigned hist[HSZ];
  __shared__ unsigned wtot[4];
  __shared__ double smaxd[4];
  __shared__ int sB, sK, scnt, sTi;
  __shared__ u64 sTv;
  __shared__ u64 cbits[256];
  __shared__ int cidx[256];
  int tid = threadIdx.x;
  int lane = tid & 63, w = tid >> 6;
  const CT* rp = cnt + (size_t)blockIdx.x * N_DIM;
  float* wp = outp + (size_t)blockIdx.x * N_DIM;

  double v[16];
  #pragma unroll
  for (int g = 0; g < 4; ++g){
    int c0 = g*1024 + tid*4;
    double4 bf = *(const double4*)&boost[c0];
    if constexpr (sizeof(CT) == 2){
      ushort4 f = *(const ushort4*)&rp[c0];
      v[g*4+0] = (double)f.x * bf.x;
      v[g*4+1] = (double)f.y * bf.y;
      v[g*4+2] = (double)f.z * bf.z;
      v[g*4+3] = (double)f.w * bf.w;
    } else {
      float4 f = *(const float4*)&rp[c0];
      v[g*4+0] = (double)f.x * bf.x;
      v[g*4+1] = (double)f.y * bf.y;
      v[g*4+2] = (double)f.z * bf.z;
      v[g*4+3] = (double)f.w * bf.w;
    }
  }

  double mx = v[0];
  #pragma unroll
  for (int e = 1; e < 16; ++e) mx = fmax(mx, v[e]);
  #pragma unroll
  for (int off = 32; off > 0; off >>= 1) mx = fmax(mx, __shfl_down(mx, off, 64));
  if (lane == 0) smaxd[w] = mx;
  #pragma unroll
  for (int i = 0; i < 17; ++i){
    int x = tid + 256*i;
    if (x < HSZ) hist[x] = 0u;
  }
  if (tid == 0) scnt = 0;
  __syncthreads();

  double M = fmax(fmax(smaxd[0], smaxd[1]), fmax(smaxd[2], smaxd[3]));
  float sF = (M > 0.0) ? (float)(4095.0 / M) : 0.0f;
  unsigned bin[16];
  #pragma unroll
  for (int e = 0; e < 16; ++e)
    bin[e] = (unsigned)fminf(4095.0f, (float)v[e] * sF);
  #pragma unroll
  for (int e = 0; e < 16; ++e) atomicAdd(&hist[PIDX(bin[e])], 1u);
  __syncthreads();

  find_bin(hist, wtot, &sB, &sK, tid, TOPK);
  int B = sB, k1 = sK;

  #pragma unroll
  for (int e = 0; e < 16; ++e){
    if (bin[e] == (unsigned)B){
      int pos = atomicAdd(&scnt, 1);
      if (pos < 256){
        int g = e >> 2, j = e & 3;
        cbits[pos] = (u64)__double_as_longlong(v[e]);
        cidx[pos] = g*1024 + tid*4 + j;
      }
    }
  }
  __syncthreads();
  int Csz = scnt; if (Csz > 256) Csz = 256;
  for (int i = tid; i < Csz; i += 256){
    u64 bi = cbits[i]; int xi = cidx[i];
    int rk = 0;
    for (int j2 = 0; j2 < Csz; ++j2){
      u64 bj = cbits[j2];
      rk += (int)((bj > bi) || (bj == bi && cidx[j2] < xi));
    }
    if (rk == k1 - 1){ sTv = bi; sTi = xi; }
  }
  __syncthreads();
  double Tv = __longlong_as_double((long long)sTv);
  int Ti = sTi;
  #pragma unroll
  for (int g = 0; g < 4; ++g){
    int c0 = g*1024 + tid*4;
    float4 o;
    o.x = (v[g*4+0] > Tv || (v[g*4+0] == Tv && (c0+0) <= Ti)) ? 1.0f : 0.0f;
    o.y = (v[g*4+1] > Tv || (v[g*4+1] == Tv && (c0+1) <= Ti)) ? 1.0f : 0.0f;
    o.z = (v[g*4+2] > Tv || (v[g*4+2] == Tv && (c0+2) <= Ti)) ? 1.0f : 0.0f;
    o.w = (v[g*4+3] > Tv || (v[g*4+3] == Tv && (c0+3) <= Ti)) ? 1.0f : 0.0f;
    *(float4*)&wp[c0] = o;
  }
}

extern "C" void kernel_launch(void* const* d_in, const int* in_sizes, int n_in,
                              void* d_out, int out_size, void* d_ws, size_t ws_size,
                              hipStream_t stream){
  (void)in_sizes; (void)n_in; (void)out_size;
  const float* X   = (const float*)d_in[0];   // x [8192][2048]
  const float* Cn  = (const float*)d_in[1];   // connection [2048][4096]
  const float* avg = (const float*)d_in[2];   // avg_activation [4096]
  float* out = (float*)d_out;                 // [8192][4096]
  char* ws = (char*)d_ws;

  double* boost = (double*)ws;                                          // 32 KB
  const size_t offA = 65536;
  unsigned char* A4 = (unsigned char*)(ws + offA);                      //  8 MB
  unsigned char* B4 = (unsigned char*)(ws + offA + (size_t)8388608);    //  4 MB
  unsigned short* CNT = (unsigned short*)(ws + offA + (size_t)25165824);// 64 MB
  const size_t need_mid  = offA + (size_t)25165824;
  const size_t need_full = need_mid + (size_t)67108864;

  if (ws_size >= need_full){
    prep_kernel<<<dim3(8705), dim3(256), 0, stream>>>(X, Cn, avg, (unsigned*)A4, B4, boost);
    gemm7_kernel<unsigned short><<<dim3(512), dim3(512), 0, stream>>>(A4, B4, CNT);
    topk_kernel<unsigned short><<<dim3(8192), dim3(256), 0, stream>>>(CNT, out, boost);
  } else if (ws_size >= need_mid){
    prep_kernel<<<dim3(8705), dim3(256), 0, stream>>>(X, Cn, avg, (unsigned*)A4, B4, boost);
    gemm7_kernel<float><<<dim3(512), dim3(512), 0, stream>>>(A4, B4, out);
    topk_kernel<float><<<dim3(8192), dim3(256), 0, stream>>>(out, out, boost);
  } else {
    prep_kernel<<<dim3(8705), dim3(256), 0, stream>>>(X, Cn, avg, (unsigned*)A4, B4, boost);
    gemm_fb_kernel<<<dim3(2048), dim3(256), 0, stream>>>(X, Cn, out);
    topk_kernel<float><<<dim3(8192), dim3(256), 0, stream>>>(out, out, boost);
  }
}

// Round 15
// 113.492 us; speedup vs baseline: 1.0533x; 1.0533x over previous
//
#include <hip/hip_runtime.h>
#include <math.h>

#define M_DIM 8192
#define K_DIM 2048
#define N_DIM 4096
#define TOPK  82

typedef short short8 __attribute__((ext_vector_type(8)));
typedef float f32x4 __attribute__((ext_vector_type(4)));
typedef float f32x16 __attribute__((ext_vector_type(16)));
typedef int   i32x4 __attribute__((ext_vector_type(4)));
typedef int   i32x8 __attribute__((ext_vector_type(8)));
typedef unsigned short ushort_t;
typedef unsigned long long u64;

__device__ __forceinline__ unsigned short f2bf(float f){
  unsigned u = __float_as_uint(f);
  unsigned r = (u + 0x7FFFu + ((u >> 16) & 1u)) >> 16;  // RNE; exact for 0.0/1.0
  return (unsigned short)r;
}

// async global->LDS, 16B per lane. LDS dest = wave-uniform base + lane*16.
__device__ __forceinline__ void gload16(const void* g, void* l){
  __builtin_amdgcn_global_load_lds(
      (const __attribute__((address_space(1))) unsigned int*)g,
      (__attribute__((address_space(3))) unsigned int*)l,
      16, 0, 0);
}

// MX-fp4 MFMA 32x32x64, scale = 1.0 (E8M0 = 127). Verified rounds 13/14.
__device__ __forceinline__ f32x16 mfma32_fp4(i32x4 a, i32x4 b, f32x16 c){
  i32x8 A; A[0]=a[0]; A[1]=a[1]; A[2]=a[2]; A[3]=a[3]; A[4]=0; A[5]=0; A[6]=0; A[7]=0;
  i32x8 B; B[0]=b[0]; B[1]=b[1]; B[2]=b[2]; B[3]=b[3]; B[4]=0; B[5]=0; B[6]=0; B[7]=0;
  return __builtin_amdgcn_mfma_scale_f32_32x32x64_f8f6f4(
      A, B, c, 4, 4, 0, 0x7F7F7F7F, 0, 0x7F7F7F7F);
}

// ---- fused prep: A-pack (0..8191) | B-pack (8192..8703) | boost (8704) ----
// (round-14 verified, unchanged) fp4 nibble: 1.0 -> 0x2, 0.0 -> 0x0 (e2m1).
// B4W wave-order layout: byte = ((g*16 + kt)*4 + c)*512 + (col&31)*16.
__global__ __launch_bounds__(256) void prep_kernel(const float* __restrict__ X,
                                                   const float* __restrict__ Cn,
                                                   const float* __restrict__ avg,
                                                   unsigned* __restrict__ A4,
                                                   unsigned char* __restrict__ B4,
                                                   double* __restrict__ boost){
  int bid = blockIdx.x;
  int tid = threadIdx.x;
  if (bid < 8192){
    size_t e0 = ((size_t)bid*256 + tid)*8;
    float4 f0 = *(const float4*)&X[e0];
    float4 f1 = *(const float4*)&X[e0 + 4];
    unsigned dw = (f0.x!=0.f?2u:0u)        | ((f0.y!=0.f?2u:0u)<<4)
                | ((f0.z!=0.f?2u:0u)<<8)   | ((f0.w!=0.f?2u:0u)<<12)
                | ((f1.x!=0.f?2u:0u)<<16)  | ((f1.y!=0.f?2u:0u)<<20)
                | ((f1.z!=0.f?2u:0u)<<24)  | ((f1.w!=0.f?2u:0u)<<28);
    A4[(size_t)bid*256 + tid] = dw;
  } else if (bid < 8704){
    __shared__ float s[128*132];
    int b = bid - 8192;
    int bk = b & 15, bn = b >> 4;          // bk = K-tile (128 elems), bn = 128-col tile
    int rr = tid >> 5, cc = (tid & 31)*4;
    #pragma unroll
    for (int p = 0; p < 16; ++p){
      int r = p*8 + rr;
      float4 f = *(const float4*)&Cn[((size_t)(bk*128 + r))*N_DIM + bn*128 + cc];
      *(float4*)&s[r*132 + cc] = f;
    }
    __syncthreads();
    int nn = tid >> 1, kh = tid & 1;       // col in tile (0..127), k-half 0/1
    unsigned dws[8];
    #pragma unroll
    for (int d = 0; d < 8; ++d){
      unsigned v = 0;
      #pragma unroll
      for (int i = 0; i < 8; ++i){
        int k = kh*64 + d*8 + i;
        v |= (s[k*132 + nn] != 0.f ? 2u : 0u) << (4*i);
      }
      dws[d] = v;
    }
    uint4 o0; o0.x=dws[0]; o0.y=dws[1]; o0.z=dws[2]; o0.w=dws[3];   // chunk 2*kh
    uint4 o1; o1.x=dws[4]; o1.y=dws[5]; o1.z=dws[6]; o1.w=dws[7];   // chunk 2*kh+1
    int g = bn*4 + (nn >> 5);              // global_col / 32
    size_t base = (((size_t)g*16 + bk)*4 + 2*kh)*512 + (size_t)(nn & 31)*16;
    *(uint4*)&B4[base]       = o0;
    *(uint4*)&B4[base + 512] = o1;
  } else {
    __shared__ double sp[4];
    __shared__ double stot;
    int lane = tid & 63, w = tid >> 6;
    double s = 0.0;
    for (int i = 0; i < 16; ++i) s += (double)avg[tid + 256*i];
    for (int off = 32; off > 0; off >>= 1) s += __shfl_down(s, off, 64);
    if (lane == 0) sp[w] = s;
    __syncthreads();
    if (tid == 0) stot = sp[0] + sp[1] + sp[2] + sp[3];
    __syncthreads();
    double tot = stot;
    for (int i = 0; i < 16; ++i){
      int j = tid + 256*i;
      double a = (double)avg[j];
      double nb = (tot - a) / 4095.0;
      boost[j] = exp(-100.0 * (a - nb));
    }
  }
}

// ---- fp4 GEMM, 256x256, 32x32x64, B direct from L2 + 1-deep REG PIPELINE ---
// Round-14 structure (numerically verified) with B-latency fix: b(t+1) loads
// issue at the top of iteration t into a second register set; ~1300 cyc of
// a-reads + MFMAs cover the L2 latency, and the barrier's vmcnt(0) guarantees
// arrival. A: LDS dbuf + paired-row swizzle + gload_lds (verified r12-r14).
template<typename OUT_T>
__global__ __launch_bounds__(512, 2) void gemm8_kernel(const unsigned char* __restrict__ A4,
                                                       const unsigned char* __restrict__ B4,
                                                       OUT_T* __restrict__ out){
  __shared__ unsigned char smem[65536];   // A dbuf: c*16384 (32 KB); epilogue reuses 64 KB
  int tid = threadIdx.x;
  int lane = tid & 63, w = tid >> 6;
  unsigned bid = blockIdx.x;
  unsigned sw = (bid & 7u)*64u + (bid >> 3);   // XCD swizzle, 512%8==0 bijective
  int bn = sw & 15, bm = sw >> 4;
  int brow = bm*256, bcol = bn*256;
  int wr = w >> 2, wc = w & 3;
  int fr = lane & 31, fq2 = lane >> 5;
  int pl = lane >> 3;                          // staging pair within 16-row group
  int sx = (lane & 7) ^ (pl & 7);
  int sp2 = sx >> 2;                           // source row parity
  int sc = sx & 3;                             // source chunk

  f32x16 acc[4][2];
  #pragma unroll
  for (int m = 0; m < 4; ++m)
    #pragma unroll
    for (int n = 0; n < 2; ++n)
      #pragma unroll
      for (int r = 0; r < 16; ++r) acc[m][n][r] = 0.f;

  auto stage = [&](int c, int kt){             // A only
    unsigned char* Ad = smem + c*16384;
    int kbase = kt*64;
    #pragma unroll
    for (int i = 0; i < 2; ++i){
      int R0 = w*32 + i*16;
      int r  = R0 + 2*pl + sp2;
      gload16(A4 + ((size_t)(brow + r))*1024 + kbase + sc*16, Ad + R0*64);
    }
  };

  auto lds_off = [&](int r, int c)->int{       // row r, 16-B chunk c (0..3)
    int pair = r >> 1;
    int s = (((r & 1) << 2) + c) ^ (pair & 7);
    return pair*128 + s*16;
  };

  // per-wave B fragment bases (g = global_col/32 = bn*8 + wc*2 + n)
  const unsigned char* bbase[2];
  #pragma unroll
  for (int n = 0; n < 2; ++n)
    bbase[n] = B4 + (((size_t)(bn*8 + wc*2 + n)*16)*4)*512 + (size_t)lane*16;

  // prologue: b(0) into current regs, A(0) staged
  i32x4 b0c[2], b1c[2], b0n[2], b1n[2];
  #pragma unroll
  for (int n = 0; n < 2; ++n){
    b0c[n] = *(const i32x4*)(bbase[n]);
    b1c[n] = *(const i32x4*)(bbase[n] + 1024);
  }
  stage(0, 0);
  __syncthreads();
  int cur = 0;
  for (int t = 0; t < 16; ++t){
    if (t < 15){
      // issue b(t+1) + A(t+1) early; latency hides under this tile's compute
      #pragma unroll
      for (int n = 0; n < 2; ++n){
        const unsigned char* bq = bbase[n] + (size_t)(t + 1)*2048;
        b0n[n] = *(const i32x4*)(bq);
        b1n[n] = *(const i32x4*)(bq + 1024);
      }
      stage(cur ^ 1, t + 1);
    }
    const unsigned char* Ah = smem + cur*16384;
    i32x4 a0[4], a1[4];
    #pragma unroll
    for (int m = 0; m < 4; ++m){
      int r = wr*128 + m*32 + fr;
      a0[m] = *(const i32x4*)&Ah[lds_off(r, fq2)];
      a1[m] = *(const i32x4*)&Ah[lds_off(r, 2 + fq2)];
    }
    #pragma unroll
    for (int m = 0; m < 4; ++m)
      #pragma unroll
      for (int n = 0; n < 2; ++n)
        acc[m][n] = mfma32_fp4(a0[m], b0c[n], acc[m][n]);
    #pragma unroll
    for (int m = 0; m < 4; ++m)
      #pragma unroll
      for (int n = 0; n < 2; ++n)
        acc[m][n] = mfma32_fp4(a1[m], b1c[n], acc[m][n]);
    __syncthreads();                       // drains A prefetch + b(t+1); buf reuse safe
    cur ^= 1;
    #pragma unroll
    for (int n = 0; n < 2; ++n){ b0c[n] = b0n[n]; b1c[n] = b1n[n]; }
  }

  if constexpr (sizeof(OUT_T) == 2){
    // u16 epilogue in two 64 KB passes (exact: counts are integers <= 2048)
    unsigned short* Ct = (unsigned short*)smem;
    #pragma unroll
    for (int p = 0; p < 2; ++p){
      if (wr == p){
        #pragma unroll
        for (int m = 0; m < 4; ++m)
          #pragma unroll
          for (int n = 0; n < 2; ++n)
            #pragma unroll
            for (int r = 0; r < 16; ++r){
              int lr = m*32 + (r & 3) + 8*(r >> 2) + 4*fq2;   // 0..127
              int lc = wc*64 + n*32 + fr;
              Ct[lr*256 + lc] = (unsigned short)(acc[m][n][r] + 0.5f);
            }
      }
      __syncthreads();
      #pragma unroll
      for (int q = 0; q < 8; ++q){
        int idx = q*8192 + tid*16;           // byte offset into 64 KB half
        int lr = idx >> 9;
        int lcb = idx & 511;
        char* gp = (char*)(out + ((size_t)(brow + p*128 + lr))*N_DIM + bcol) + lcb;
        *(uint4*)gp = *(const uint4*)&smem[idx];
      }
      __syncthreads();
    }
  } else {
    #pragma unroll
    for (int m = 0; m < 4; ++m)
      #pragma unroll
      for (int n = 0; n < 2; ++n)
        #pragma unroll
        for (int r = 0; r < 16; ++r){
          int row = brow + wr*128 + m*32 + (r & 3) + 8*(r >> 2) + 4*fq2;
          int col = bcol + wc*64 + n*32 + fr;
          out[((size_t)row)*N_DIM + col] = (OUT_T)acc[m][n][r];
        }
  }
}

// ---------------- fallback GEMM (tiny ws): bf16 reg-staged ------------------
__global__ __launch_bounds__(256) void gemm_fb_kernel(const float* __restrict__ X,
                                                      const float* __restrict__ Cn,
                                                      float* __restrict__ out){
  __shared__ ushort_t As[128*32];
  __shared__ ushort_t Bs[128*32];
  int tid = threadIdx.x;
  int bn = blockIdx.x & 31, bm = blockIdx.x >> 5;
  int brow = bm * 128, bcol = bn * 128;
  int lane = tid & 63, w = tid >> 6;
  int wr = w >> 1, wc = w & 1;
  int fr = lane & 15, fq = lane >> 4;
  f32x4 acc[4][4];
  for (int m = 0; m < 4; ++m)
    for (int n = 0; n < 4; ++n)
      acc[m][n] = (f32x4){0.f, 0.f, 0.f, 0.f};
  int r2 = tid >> 1, h = tid & 1;
  int kr = tid >> 3, seg = tid & 7;
  for (int kk = 0; kk < K_DIM; kk += 32){
    __syncthreads();
    const float* ga = X + ((size_t)(brow + r2))*K_DIM + kk + h*16;
    unsigned pk[8];
    for (int q = 0; q < 4; ++q){
      float4 f = *(const float4*)(ga + q*4);
      pk[q*2]   = (unsigned)f2bf(f.x) | ((unsigned)f2bf(f.y) << 16);
      pk[q*2+1] = (unsigned)f2bf(f.z) | ((unsigned)f2bf(f.w) << 16);
    }
    uint4 u0; u0.x = pk[0]; u0.y = pk[1]; u0.z = pk[2]; u0.w = pk[3];
    uint4 u1; u1.x = pk[4]; u1.y = pk[5]; u1.z = pk[6]; u1.w = pk[7];
    *(uint4*)&As[r2*32 + h*16]     = u0;
    *(uint4*)&As[r2*32 + h*16 + 8] = u1;
    const float* gb = Cn + ((size_t)(kk + kr))*N_DIM + bcol + seg*16;
    for (int q = 0; q < 4; ++q){
      float4 f = *(const float4*)(gb + q*4);
      Bs[(seg*16 + q*4 + 0)*32 + kr] = f2bf(f.x);
      Bs[(seg*16 + q*4 + 1)*32 + kr] = f2bf(f.y);
      Bs[(seg*16 + q*4 + 2)*32 + kr] = f2bf(f.z);
      Bs[(seg*16 + q*4 + 3)*32 + kr] = f2bf(f.w);
    }
    __syncthreads();
    short8 a[4], b[4];
    for (int m = 0; m < 4; ++m) a[m] = *(const short8*)&As[(wr*64 + m*16 + fr)*32 + fq*8];
    for (int n = 0; n < 4; ++n) b[n] = *(const short8*)&Bs[(wc*64 + n*16 + fr)*32 + fq*8];
    for (int m = 0; m < 4; ++m)
      for (int n = 0; n < 4; ++n)
        acc[m][n] = __builtin_amdgcn_mfma_f32_16x16x32_bf16(a[m], b[n], acc[m][n], 0, 0, 0);
  }
  for (int m = 0; m < 4; ++m)
    for (int n = 0; n < 4; ++n){
      int row = brow + wr*64 + m*16 + fq*4;
      int col = bcol + wc*64 + n*16 + fr;
      for (int j = 0; j < 4; ++j)
        out[((size_t)(row + j))*N_DIM + col] = acc[m][n][j];
    }
}

// ---------------- per-row exact top-82 -> one-hot (round-11, verified) ------
#define PIDX(x) ((x) + ((x) >> 5))
#define HSZ 4224

__device__ __forceinline__ void find_bin(const unsigned* hist, unsigned* wtot,
                                         int* pB, int* pK, int tid, int Kt){
  int lane = tid & 63, w = tid >> 6;
  unsigned s = 0;
  #pragma unroll
  for (int b = 0; b < 16; ++b) s += hist[PIDX(tid*16 + b)];
  unsigned S = s;
  #pragma unroll
  for (int off = 1; off < 64; off <<= 1){
    unsigned T = __shfl_down(S, off, 64);
    if (lane + off < 64) S += T;
  }
  if (lane == 0) wtot[w] = S;
  __syncthreads();
  unsigned above = 0;
  for (int w2 = w + 1; w2 < 4; ++w2) above += wtot[w2];
  unsigned St = S + above;
  unsigned Sn = St - s;
  if (St >= (unsigned)Kt && Sn < (unsigned)Kt){
    unsigned cum = Sn;
    for (int b = 15; b >= 0; --b){
      unsigned hb = hist[PIDX(tid*16 + b)];
      cum += hb;
      if (cum >= (unsigned)Kt){ *pB = tid*16 + b; *pK = Kt - (int)(cum - hb); break; }
    }
  }
  __syncthreads();
}

template<typename CT>
__global__ __launch_bounds__(256) void topk_kernel(const CT* __restrict__ cnt,
                                                   float* __restrict__ outp,
                                                   const double* __restrict__ boost){
  __shared__ unsigned hist[HSZ];
  __shared__ unsigned wtot[4];
  __shared__ double smaxd[4];
  __shared__ int sB, sK, scnt, sTi;
  __shared__ u64 sTv;
  __shared__ u64 cbits[256];
  __shared__ int cidx[256];
  int tid = threadIdx.x;
  int lane = tid & 63, w = tid >> 6;
  const CT* rp = cnt + (size_t)blockIdx.x * N_DIM;
  float* wp = outp + (size_t)blockIdx.x * N_DIM;

  double v[16];
  #pragma unroll
  for (int g = 0; g < 4; ++g){
    int c0 = g*1024 + tid*4;
    double4 bf = *(const double4*)&boost[c0];
    if constexpr (sizeof(CT) == 2){
      ushort4 f = *(const ushort4*)&rp[c0];
      v[g*4+0] = (double)f.x * bf.x;
      v[g*4+1] = (double)f.y * bf.y;
      v[g*4+2] = (double)f.z * bf.z;
      v[g*4+3] = (double)f.w * bf.w;
    } else {
      float4 f = *(const float4*)&rp[c0];
      v[g*4+0] = (double)f.x * bf.x;
      v[g*4+1] = (double)f.y * bf.y;
      v[g*4+2] = (double)f.z * bf.z;
      v[g*4+3] = (double)f.w * bf.w;
    }
  }

  double mx = v[0];
  #pragma unroll
  for (int e = 1; e < 16; ++e) mx = fmax(mx, v[e]);
  #pragma unroll
  for (int off = 32; off > 0; off >>= 1) mx = fmax(mx, __shfl_down(mx, off, 64));
  if (lane == 0) smaxd[w] = mx;
  #pragma unroll
  for (int i = 0; i < 17; ++i){
    int x = tid + 256*i;
    if (x < HSZ) hist[x] = 0u;
  }
  if (tid == 0) scnt = 0;
  __syncthreads();

  double M = fmax(fmax(smaxd[0], smaxd[1]), fmax(smaxd[2], smaxd[3]));
  float sF = (M > 0.0) ? (float)(4095.0 / M) : 0.0f;
  unsigned bin[16];
  #pragma unroll
  for (int e = 0; e < 16; ++e)
    bin[e] = (unsigned)fminf(4095.0f, (float)v[e] * sF);
  #pragma unroll
  for (int e = 0; e < 16; ++e) atomicAdd(&hist[PIDX(bin[e])], 1u);
  __syncthreads();

  find_bin(hist, wtot, &sB, &sK, tid, TOPK);
  int B = sB, k1 = sK;

  #pragma unroll
  for (int e = 0; e < 16; ++e){
    if (bin[e] == (unsigned)B){
      int pos = atomicAdd(&scnt, 1);
      if (pos < 256){
        int g = e >> 2, j = e & 3;
        cbits[pos] = (u64)__double_as_longlong(v[e]);
        cidx[pos] = g*1024 + tid*4 + j;
      }
    }
  }
  __syncthreads();
  int Csz = scnt; if (Csz > 256) Csz = 256;
  for (int i = tid; i < Csz; i += 256){
    u64 bi = cbits[i]; int xi = cidx[i];
    int rk = 0;
    for (int j2 = 0; j2 < Csz; ++j2){
      u64 bj = cbits[j2];
      rk += (int)((bj > bi) || (bj == bi && cidx[j2] < xi));
    }
    if (rk == k1 - 1){ sTv = bi; sTi = xi; }
  }
  __syncthreads();
  double Tv = __longlong_as_double((long long)sTv);
  int Ti = sTi;
  #pragma unroll
  for (int g = 0; g < 4; ++g){
    int c0 = g*1024 + tid*4;
    float4 o;
    o.x = (v[g*4+0] > Tv || (v[g*4+0] == Tv && (c0+0) <= Ti)) ? 1.0f : 0.0f;
    o.y = (v[g*4+1] > Tv || (v[g*4+1] == Tv && (c0+1) <= Ti)) ? 1.0f : 0.0f;
    o.z = (v[g*4+2] > Tv || (v[g*4+2] == Tv && (c0+2) <= Ti)) ? 1.0f : 0.0f;
    o.w = (v[g*4+3] > Tv || (v[g*4+3] == Tv && (c0+3) <= Ti)) ? 1.0f : 0.0f;
    *(float4*)&wp[c0] = o;
  }
}

extern "C" void kernel_launch(void* const* d_in, const int* in_sizes, int n_in,
                              void* d_out, int out_size, void* d_ws, size_t ws_size,
                              hipStream_t stream){
  (void)in_sizes; (void)n_in; (void)out_size;
  const float* X   = (const float*)d_in[0];   // x [8192][2048]
  const float* Cn  = (const float*)d_in[1];   // connection [2048][4096]
  const float* avg = (const float*)d_in[2];   // avg_activation [4096]
  float* out = (float*)d_out;                 // [8192][4096]
  char* ws = (char*)d_ws;

  double* boost = (double*)ws;                                          // 32 KB
  const size_t offA = 65536;
  unsigned char* A4 = (unsigned char*)(ws + offA);                      //  8 MB
  unsigned char* B4 = (unsigned char*)(ws + offA + (size_t)8388608);    //  4 MB
  unsigned short* CNT = (unsigned short*)(ws + offA + (size_t)25165824);// 64 MB
  const size_t need_mid  = offA + (size_t)25165824;
  const size_t need_full = need_mid + (size_t)67108864;

  if (ws_size >= need_full){
    prep_kernel<<<dim3(8705), dim3(256), 0, stream>>>(X, Cn, avg, (unsigned*)A4, B4, boost);
    gemm8_kernel<unsigned short><<<dim3(512), dim3(512), 0, stream>>>(A4, B4, CNT);
    topk_kernel<unsigned short><<<dim3(8192), dim3(256), 0, stream>>>(CNT, out, boost);
  } else if (ws_size >= need_mid){
    prep_kernel<<<dim3(8705), dim3(256), 0, stream>>>(X, Cn, avg, (unsigned*)A4, B4, boost);
    gemm8_kernel<float><<<dim3(512), dim3(512), 0, stream>>>(A4, B4, out);
    topk_kernel<float><<<dim3(8192), dim3(256), 0, stream>>>(out, out, boost);
  } else {
    prep_kernel<<<dim3(8705), dim3(256), 0, stream>>>(X, Cn, avg, (unsigned*)A4, B4, boost);
    gemm_fb_kernel<<<dim3(2048), dim3(256), 0, stream>>>(X, Cn, out);
    topk_kernel<float><<<dim3(8192), dim3(256), 0, stream>>>(out, out, boost);
  }
}

// Round 16
// 110.951 us; speedup vs baseline: 1.0775x; 1.0229x over previous
//
#include <hip/hip_runtime.h>
#include <math.h>

#define M_DIM 8192
#define K_DIM 2048
#define N_DIM 4096
#define TOPK  82

typedef short short8 __attribute__((ext_vector_type(8)));
typedef float f32x4 __attribute__((ext_vector_type(4)));
typedef int   i32x4 __attribute__((ext_vector_type(4)));
typedef int   i32x8 __attribute__((ext_vector_type(8)));
typedef unsigned short ushort_t;
typedef unsigned long long u64;

__device__ __forceinline__ unsigned short f2bf(float f){
  unsigned u = __float_as_uint(f);
  unsigned r = (u + 0x7FFFu + ((u >> 16) & 1u)) >> 16;  // RNE; exact for 0.0/1.0
  return (unsigned short)r;
}

// async global->LDS, 16B per lane. LDS dest = wave-uniform base + lane*16.
__device__ __forceinline__ void gload16(const void* g, void* l){
  __builtin_amdgcn_global_load_lds(
      (const __attribute__((address_space(1))) unsigned int*)g,
      (__attribute__((address_space(3))) unsigned int*)l,
      16, 0, 0);
}

// MX-fp4 MFMA 16x16x128, scale = 1.0 (E8M0 = 127). fp4 operands live in the
// low 4 regs of the 8-reg field (cbsz=blgp=4 -> e2m1). Products 0/1 and fp32
// partial sums <= 2048 are exact. (Round-12 verified kernel, best measured.)
__device__ __forceinline__ f32x4 mfma_fp4(i32x4 a, i32x4 b, f32x4 c){
  i32x8 A; A[0]=a[0]; A[1]=a[1]; A[2]=a[2]; A[3]=a[3]; A[4]=0; A[5]=0; A[6]=0; A[7]=0;
  i32x8 B; B[0]=b[0]; B[1]=b[1]; B[2]=b[2]; B[3]=b[3]; B[4]=0; B[5]=0; B[6]=0; B[7]=0;
  return __builtin_amdgcn_mfma_scale_f32_16x16x128_f8f6f4(
      A, B, c, 4, 4, 0, 0x7F7F7F7F, 0, 0x7F7F7F7F);
}

// ---- fused prep: A-pack (0..8191) | B-pack (8192..8703) | boost (8704) ----
// fp4 nibble: 1.0 -> 0x2, 0.0 -> 0x0 (e2m1). Element j of a dword at bits
// 4*(j&7), dword j>>3 (little-endian, same convention as fp8 bytes).
__global__ __launch_bounds__(256) void prep_kernel(const float* __restrict__ X,
                                                   const float* __restrict__ Cn,
                                                   const float* __restrict__ avg,
                                                   unsigned* __restrict__ A4,
                                                   unsigned char* __restrict__ B4,
                                                   double* __restrict__ boost){
  int bid = blockIdx.x;
  int tid = threadIdx.x;
  if (bid < 8192){
    size_t e0 = ((size_t)bid*256 + tid)*8;
    float4 f0 = *(const float4*)&X[e0];
    float4 f1 = *(const float4*)&X[e0 + 4];
    unsigned dw = (f0.x!=0.f?2u:0u)        | ((f0.y!=0.f?2u:0u)<<4)
                | ((f0.z!=0.f?2u:0u)<<8)   | ((f0.w!=0.f?2u:0u)<<12)
                | ((f1.x!=0.f?2u:0u)<<16)  | ((f1.y!=0.f?2u:0u)<<20)
                | ((f1.z!=0.f?2u:0u)<<24)  | ((f1.w!=0.f?2u:0u)<<28);
    A4[(size_t)bid*256 + tid] = dw;
  } else if (bid < 8704){
    __shared__ float s[128*132];
    int b = bid - 8192;
    int bk = b & 15, bn = b >> 4;
    int rr = tid >> 5, cc = (tid & 31)*4;
    #pragma unroll
    for (int p = 0; p < 16; ++p){
      int r = p*8 + rr;
      float4 f = *(const float4*)&Cn[((size_t)(bk*128 + r))*N_DIM + bn*128 + cc];
      *(float4*)&s[r*132 + cc] = f;
    }
    __syncthreads();
    int nn = tid >> 1, kh = tid & 1;       // n in 0..127, k-half 0/1
    unsigned dws[8];
    #pragma unroll
    for (int d = 0; d < 8; ++d){
      unsigned v = 0;
      #pragma unroll
      for (int i = 0; i < 8; ++i){
        int k = kh*64 + d*8 + i;
        v |= (s[k*132 + nn] != 0.f ? 2u : 0u) << (4*i);
      }
      dws[d] = v;
    }
    uint4 o0; o0.x=dws[0]; o0.y=dws[1]; o0.z=dws[2]; o0.w=dws[3];
    uint4 o1; o1.x=dws[4]; o1.y=dws[5]; o1.z=dws[6]; o1.w=dws[7];
    size_t rowb = (size_t)(bn*128 + nn)*1024 + bk*64 + kh*32;
    *(uint4*)&B4[rowb]      = o0;
    *(uint4*)&B4[rowb + 16] = o1;
  } else {
    __shared__ double sp[4];
    __shared__ double stot;
    int lane = tid & 63, w = tid >> 6;
    double s = 0.0;
    for (int i = 0; i < 16; ++i) s += (double)avg[tid + 256*i];
    for (int off = 32; off > 0; off >>= 1) s += __shfl_down(s, off, 64);
    if (lane == 0) sp[w] = s;
    __syncthreads();
    if (tid == 0) stot = sp[0] + sp[1] + sp[2] + sp[3];
    __syncthreads();
    double tot = stot;
    for (int i = 0; i < 16; ++i){
      int j = tid + 256*i;
      double a = (double)avg[j];
      double nb = (tot - a) / 4095.0;
      boost[j] = exp(-100.0 * (a - nb));
    }
  }
}

// ---- fp4 GEMM, 256x256, BK=128 elems (64 B), 2-phase @ 64 KB, 2 blocks/CU --
// (round-12 verified, best measured) Rows are 64 B per K-tile, paired-row
// swizzle (pair=r>>1, slot s=((r&1)*4+c)^(pair&7)), linear gload_lds dest +
// inverse-swizzled global source, fragment chunk c = fq. 16 K-tiles.
template<typename OUT_T>
__global__ __launch_bounds__(512, 2) void gemm5f_kernel(const unsigned char* __restrict__ A4,
                                                        const unsigned char* __restrict__ B4,
                                                        OUT_T* __restrict__ out){
  __shared__ unsigned char smem[65536];   // A: c*16384 | B: 32768 + c*16384
  int tid = threadIdx.x;
  int lane = tid & 63, w = tid >> 6;
  unsigned bid = blockIdx.x;
  unsigned sw = (bid & 7u)*64u + (bid >> 3);   // XCD swizzle, 512%8==0 bijective
  int bn = sw & 15, bm = sw >> 4;
  int brow = bm*256, bcol = bn*256;
  int wr = w >> 2, wc = w & 3;
  int fr = lane & 15, fq = lane >> 4;
  int pl = lane >> 3;                          // staging pair within 16-row group
  int sx = (lane & 7) ^ (pl & 7);
  int sp2 = sx >> 2;                           // source row parity
  int sc = sx & 3;                             // source chunk

  f32x4 acc[8][4];
  #pragma unroll
  for (int m = 0; m < 8; ++m)
    #pragma unroll
    for (int n = 0; n < 4; ++n) acc[m][n] = (f32x4){0.f,0.f,0.f,0.f};

  auto stage = [&](int c, int kt){
    unsigned char* Ad = smem + c*16384;
    unsigned char* Bd = smem + 32768 + c*16384;
    int kbase = kt*64;                         // bytes within the 1024-B row
    #pragma unroll
    for (int i = 0; i < 2; ++i){
      int R0 = w*32 + i*16;
      int r  = R0 + 2*pl + sp2;
      gload16(A4 + ((size_t)(brow + r))*1024 + kbase + sc*16, Ad + R0*64);
      gload16(B4 + ((size_t)(bcol + r))*1024 + kbase + sc*16, Bd + R0*64);
    }
  };

  auto lds_off = [&](int r)->int{
    int pair = r >> 1;
    int s = (((r & 1) << 2) + fq) ^ (pair & 7);
    return pair*128 + s*16;
  };

  stage(0, 0);
  __syncthreads();
  int cur = 0;
  for (int t = 0; t < 16; ++t){
    if (t < 15) stage(cur ^ 1, t + 1);     // prefetch flies under compute
    const unsigned char* Ah = smem + cur*16384;
    const unsigned char* Bh = smem + 32768 + cur*16384;
    i32x4 a[8], b[4];
    #pragma unroll
    for (int n = 0; n < 4; ++n)
      b[n] = *(const i32x4*)&Bh[lds_off(wc*64 + n*16 + fr)];
    #pragma unroll
    for (int m = 0; m < 8; ++m)
      a[m] = *(const i32x4*)&Ah[lds_off(wr*128 + m*16 + fr)];
    #pragma unroll
    for (int m = 0; m < 8; ++m)
      #pragma unroll
      for (int n = 0; n < 4; ++n)
        acc[m][n] = mfma_fp4(a[m], b[n], acc[m][n]);
    __syncthreads();                       // drains prefetch; protects buf reuse
    cur ^= 1;
  }

  if constexpr (sizeof(OUT_T) == 2){
    // u16 epilogue in two 64 KB passes (exact: counts are integers <= 2048)
    unsigned short* Ct = (unsigned short*)smem;
    #pragma unroll
    for (int p = 0; p < 2; ++p){
      if (wr == p){
        #pragma unroll
        for (int m = 0; m < 8; ++m)
          #pragma unroll
          for (int n = 0; n < 4; ++n){
            int lr = m*16 + fq*4;            // 0..127 within this half
            int lc = wc*64 + n*16 + fr;
            #pragma unroll
            for (int j = 0; j < 4; ++j)
              Ct[(lr + j)*256 + lc] = (unsigned short)(acc[m][n][j] + 0.5f);
          }
      }
      __syncthreads();
      #pragma unroll
      for (int q = 0; q < 8; ++q){
        int idx = q*8192 + tid*16;           // byte offset into 64 KB half
        int lr = idx >> 9;
        int lcb = idx & 511;
        char* gp = (char*)(out + ((size_t)(brow + p*128 + lr))*N_DIM + bcol) + lcb;
        *(uint4*)gp = *(const uint4*)&smem[idx];
      }
      __syncthreads();
    }
  } else {
    #pragma unroll
    for (int m = 0; m < 8; ++m)
      #pragma unroll
      for (int n = 0; n < 4; ++n){
        int row = brow + wr*128 + m*16 + fq*4;
        int col = bcol + wc*64 + n*16 + fr;
        #pragma unroll
        for (int j = 0; j < 4; ++j)
          out[((size_t)(row + j))*N_DIM + col] = (OUT_T)acc[m][n][j];
      }
  }
}

// ---------------- fallback GEMM (tiny ws): bf16 reg-staged ------------------
__global__ __launch_bounds__(256) void gemm_fb_kernel(const float* __restrict__ X,
                                                      const float* __restrict__ Cn,
                                                      float* __restrict__ out){
  __shared__ ushort_t As[128*32];
  __shared__ ushort_t Bs[128*32];
  int tid = threadIdx.x;
  int bn = blockIdx.x & 31, bm = blockIdx.x >> 5;
  int brow = bm * 128, bcol = bn * 128;
  int lane = tid & 63, w = tid >> 6;
  int wr = w >> 1, wc = w & 1;
  int fr = lane & 15, fq = lane >> 4;
  f32x4 acc[4][4];
  for (int m = 0; m < 4; ++m)
    for (int n = 0; n < 4; ++n)
      acc[m][n] = (f32x4){0.f, 0.f, 0.f, 0.f};
  int r2 = tid >> 1, h = tid & 1;
  int kr = tid >> 3, seg = tid & 7;
  for (int kk = 0; kk < K_DIM; kk += 32){
    __syncthreads();
    const float* ga = X + ((size_t)(brow + r2))*K_DIM + kk + h*16;
    unsigned pk[8];
    for (int q = 0; q < 4; ++q){
      float4 f = *(const float4*)(ga + q*4);
      pk[q*2]   = (unsigned)f2bf(f.x) | ((unsigned)f2bf(f.y) << 16);
      pk[q*2+1] = (unsigned)f2bf(f.z) | ((unsigned)f2bf(f.w) << 16);
    }
    uint4 u0; u0.x = pk[0]; u0.y = pk[1]; u0.z = pk[2]; u0.w = pk[3];
    uint4 u1; u1.x = pk[4]; u1.y = pk[5]; u1.z = pk[6]; u1.w = pk[7];
    *(uint4*)&As[r2*32 + h*16]     = u0;
    *(uint4*)&As[r2*32 + h*16 + 8] = u1;
    const float* gb = Cn + ((size_t)(kk + kr))*N_DIM + bcol + seg*16;
    for (int q = 0; q < 4; ++q){
      float4 f = *(const float4*)(gb + q*4);
      Bs[(seg*16 + q*4 + 0)*32 + kr] = f2bf(f.x);
      Bs[(seg*16 + q*4 + 1)*32 + kr] = f2bf(f.y);
      Bs[(seg*16 + q*4 + 2)*32 + kr] = f2bf(f.z);
      Bs[(seg*16 + q*4 + 3)*32 + kr] = f2bf(f.w);
    }
    __syncthreads();
    short8 a[4], b[4];
    for (int m = 0; m < 4; ++m) a[m] = *(const short8*)&As[(wr*64 + m*16 + fr)*32 + fq*8];
    for (int n = 0; n < 4; ++n) b[n] = *(const short8*)&Bs[(wc*64 + n*16 + fr)*32 + fq*8];
    for (int m = 0; m < 4; ++m)
      for (int n = 0; n < 4; ++n)
        acc[m][n] = __builtin_amdgcn_mfma_f32_16x16x32_bf16(a[m], b[n], acc[m][n], 0, 0, 0);
  }
  for (int m = 0; m < 4; ++m)
    for (int n = 0; n < 4; ++n){
      int row = brow + wr*64 + m*16 + fq*4;
      int col = bcol + wc*64 + n*16 + fr;
      for (int j = 0; j < 4; ++j)
        out[((size_t)(row + j))*N_DIM + col] = acc[m][n][j];
    }
}

// ---------------- per-row exact top-82 -> one-hot (round-11, verified) ------
#define PIDX(x) ((x) + ((x) >> 5))
#define HSZ 4224

__device__ __forceinline__ void find_bin(const unsigned* hist, unsigned* wtot,
                                         int* pB, int* pK, int tid, int Kt){
  int lane = tid & 63, w = tid >> 6;
  unsigned s = 0;
  #pragma unroll
  for (int b = 0; b < 16; ++b) s += hist[PIDX(tid*16 + b)];
  unsigned S = s;
  #pragma unroll
  for (int off = 1; off < 64; off <<= 1){
    unsigned T = __shfl_down(S, off, 64);
    if (lane + off < 64) S += T;
  }
  if (lane == 0) wtot[w] = S;
  __syncthreads();
  unsigned above = 0;
  for (int w2 = w + 1; w2 < 4; ++w2) above += wtot[w2];
  unsigned St = S + above;
  unsigned Sn = St - s;
  if (St >= (unsigned)Kt && Sn < (unsigned)Kt){
    unsigned cum = Sn;
    for (int b = 15; b >= 0; --b){
      unsigned hb = hist[PIDX(tid*16 + b)];
      cum += hb;
      if (cum >= (unsigned)Kt){ *pB = tid*16 + b; *pK = Kt - (int)(cum - hb); break; }
    }
  }
  __syncthreads();
}

template<typename CT>
__global__ __launch_bounds__(256) void topk_kernel(const CT* __restrict__ cnt,
                                                   float* __restrict__ outp,
                                                   const double* __restrict__ boost){
  __shared__ unsigned hist[HSZ];
  __shared__ unsigned wtot[4];
  __shared__ double smaxd[4];
  __shared__ int sB, sK, scnt, sTi;
  __shared__ u64 sTv;
  __shared__ u64 cbits[256];
  __shared__ int cidx[256];
  int tid = threadIdx.x;
  int lane = tid & 63, w = tid >> 6;
  const CT* rp = cnt + (size_t)blockIdx.x * N_DIM;
  float* wp = outp + (size_t)blockIdx.x * N_DIM;

  double v[16];
  #pragma unroll
  for (int g = 0; g < 4; ++g){
    int c0 = g*1024 + tid*4;
    double4 bf = *(const double4*)&boost[c0];
    if constexpr (sizeof(CT) == 2){
      ushort4 f = *(const ushort4*)&rp[c0];
      v[g*4+0] = (double)f.x * bf.x;
      v[g*4+1] = (double)f.y * bf.y;
      v[g*4+2] = (double)f.z * bf.z;
      v[g*4+3] = (double)f.w * bf.w;
    } else {
      float4 f = *(const float4*)&rp[c0];
      v[g*4+0] = (double)f.x * bf.x;
      v[g*4+1] = (double)f.y * bf.y;
      v[g*4+2] = (double)f.z * bf.z;
      v[g*4+3] = (double)f.w * bf.w;
    }
  }

  double mx = v[0];
  #pragma unroll
  for (int e = 1; e < 16; ++e) mx = fmax(mx, v[e]);
  #pragma unroll
  for (int off = 32; off > 0; off >>= 1) mx = fmax(mx, __shfl_down(mx, off, 64));
  if (lane == 0) smaxd[w] = mx;
  #pragma unroll
  for (int i = 0; i < 17; ++i){
    int x = tid + 256*i;
    if (x < HSZ) hist[x] = 0u;
  }
  if (tid == 0) scnt = 0;
  __syncthreads();

  double M = fmax(fmax(smaxd[0], smaxd[1]), fmax(smaxd[2], smaxd[3]));
  float sF = (M > 0.0) ? (float)(4095.0 / M) : 0.0f;
  unsigned bin[16];
  #pragma unroll
  for (int e = 0; e < 16; ++e)
    bin[e] = (unsigned)fminf(4095.0f, (float)v[e] * sF);
  #pragma unroll
  for (int e = 0; e < 16; ++e) atomicAdd(&hist[PIDX(bin[e])], 1u);
  __syncthreads();

  find_bin(hist, wtot, &sB, &sK, tid, TOPK);
  int B = sB, k1 = sK;

  #pragma unroll
  for (int e = 0; e < 16; ++e){
    if (bin[e] == (unsigned)B){
      int pos = atomicAdd(&scnt, 1);
      if (pos < 256){
        int g = e >> 2, j = e & 3;
        cbits[pos] = (u64)__double_as_longlong(v[e]);
        cidx[pos] = g*1024 + tid*4 + j;
      }
    }
  }
  __syncthreads();
  int Csz = scnt; if (Csz > 256) Csz = 256;
  for (int i = tid; i < Csz; i += 256){
    u64 bi = cbits[i]; int xi = cidx[i];
    int rk = 0;
    for (int j2 = 0; j2 < Csz; ++j2){
      u64 bj = cbits[j2];
      rk += (int)((bj > bi) || (bj == bi && cidx[j2] < xi));
    }
    if (rk == k1 - 1){ sTv = bi; sTi = xi; }
  }
  __syncthreads();
  double Tv = __longlong_as_double((long long)sTv);
  int Ti = sTi;
  #pragma unroll
  for (int g = 0; g < 4; ++g){
    int c0 = g*1024 + tid*4;
    float4 o;
    o.x = (v[g*4+0] > Tv || (v[g*4+0] == Tv && (c0+0) <= Ti)) ? 1.0f : 0.0f;
    o.y = (v[g*4+1] > Tv || (v[g*4+1] == Tv && (c0+1) <= Ti)) ? 1.0f : 0.0f;
    o.z = (v[g*4+2] > Tv || (v[g*4+2] == Tv && (c0+2) <= Ti)) ? 1.0f : 0.0f;
    o.w = (v[g*4+3] > Tv || (v[g*4+3] == Tv && (c0+3) <= Ti)) ? 1.0f : 0.0f;
    *(float4*)&wp[c0] = o;
  }
}

extern "C" void kernel_launch(void* const* d_in, const int* in_sizes, int n_in,
                              void* d_out, int out_size, void* d_ws, size_t ws_size,
                              hipStream_t stream){
  (void)in_sizes; (void)n_in; (void)out_size;
  const float* X   = (const float*)d_in[0];   // x [8192][2048]
  const float* Cn  = (const float*)d_in[1];   // connection [2048][4096]
  const float* avg = (const float*)d_in[2];   // avg_activation [4096]
  float* out = (float*)d_out;                 // [8192][4096]
  char* ws = (char*)d_ws;

  double* boost = (double*)ws;                                          // 32 KB
  const size_t offA = 65536;
  unsigned char* A4 = (unsigned char*)(ws + offA);                      //  8 MB
  unsigned char* B4 = (unsigned char*)(ws + offA + (size_t)8388608);    //  4 MB
  unsigned short* CNT = (unsigned short*)(ws + offA + (size_t)25165824);// 64 MB
  const size_t need_mid  = offA + (size_t)25165824;
  const size_t need_full = need_mid + (size_t)67108864;

  if (ws_size >= need_full){
    prep_kernel<<<dim3(8705), dim3(256), 0, stream>>>(X, Cn, avg, (unsigned*)A4, B4, boost);
    gemm5f_kernel<unsigned short><<<dim3(512), dim3(512), 0, stream>>>(A4, B4, CNT);
    topk_kernel<unsigned short><<<dim3(8192), dim3(256), 0, stream>>>(CNT, out, boost);
  } else if (ws_size >= need_mid){
    prep_kernel<<<dim3(8705), dim3(256), 0, stream>>>(X, Cn, avg, (unsigned*)A4, B4, boost);
    gemm5f_kernel<float><<<dim3(512), dim3(512), 0, stream>>>(A4, B4, out);
    topk_kernel<float><<<dim3(8192), dim3(256), 0, stream>>>(out, out, boost);
  } else {
    prep_kernel<<<dim3(8705), dim3(256), 0, stream>>>(X, Cn, avg, (unsigned*)A4, B4, boost);
    gemm_fb_kernel<<<dim3(2048), dim3(256), 0, stream>>>(X, Cn, out);
    topk_kernel<float><<<dim3(8192), dim3(256), 0, stream>>>(out, out, boost);
  }
}